// Round 2
// baseline (674.048 us; speedup 1.0000x reference)
//
#include <hip/hip_runtime.h>
#include <math.h>

typedef unsigned short u16;
typedef unsigned int   u32;
typedef __attribute__((ext_vector_type(8))) short bh8;   // 8 bf16 (4 VGPR)
typedef __attribute__((ext_vector_type(4))) float f4;    // 4 fp32 acc

#define TM 128
#define TN 128
#define TK 32
#define LDT 40   // padded LDS k-stride (bf16 elems): 80B rows -> 2-way bank alias (free)

__device__ __forceinline__ u16 f2b(float f) {
  u32 u = __builtin_bit_cast(u32, f);
  u += 0x7fffu + ((u >> 16) & 1u);   // round-to-nearest-even
  return (u16)(u >> 16);
}
__device__ __forceinline__ float b2f(u16 b) {
  u32 u = ((u32)b) << 16;
  return __builtin_bit_cast(float, u);
}
__device__ __forceinline__ float gelu_f(float x) {
  return 0.5f * x * (1.0f + erff(x * 0.70710678118654752f));
}

// ---------------- routing ----------------
__global__ __launch_bounds__(128) void init_routing(int* __restrict__ R) {
  R[threadIdx.x] = 0;
}

__global__ __launch_bounds__(256) void hist_kernel(const int* __restrict__ eidx,
                                                   const int* __restrict__ hasp,
                                                   int* __restrict__ R,
                                                   int* __restrict__ grp) {
  int t = blockIdx.x * 256 + threadIdx.x;
  int g = eidx[t] * 2 + (hasp[t] != 0 ? 1 : 0);
  grp[t] = g;
  atomicAdd(&R[g], 1);
}

__global__ __launch_bounds__(64) void scan_kernel(int* __restrict__ R) {
  if (threadIdx.x == 0) {
    int* cnt = R; int* cur = R + 16; int* gs = R + 32; int* to = R + 64;
    gs[0] = 0; to[0] = 0;
    for (int g = 0; g < 16; g++) {
      gs[g + 1] = gs[g] + cnt[g];
      cur[g] = gs[g];
      to[g + 1] = to[g] + (cnt[g] + TM - 1) / TM;
    }
  }
}

__global__ __launch_bounds__(256) void scatter_kernel(const int* __restrict__ grp,
                                                      int* __restrict__ R,
                                                      int* __restrict__ perm) {
  int t = blockIdx.x * 256 + threadIdx.x;
  int g = grp[t];
  int pos = atomicAdd(&R[16 + g], 1);
  perm[pos] = t;
}

// gather raw_state (fp32) into grouped order, convert to bf16
__global__ __launch_bounds__(256) void gather_kernel(const float* __restrict__ raw,
                                                     const int* __restrict__ perm,
                                                     u16* __restrict__ Xg) {
  int t = blockIdx.x * 256 + threadIdx.x;
  int pos = t >> 6, ln = t & 63;
  int orig = perm[pos];
  Xg[(size_t)pos * 64 + ln] = f2b(raw[(size_t)orig * 64 + ln]);
}

// ---------------- weight transpose+convert: src fp32 [R][C] -> dst bf16 [C][R] ----------------
__global__ __launch_bounds__(256) void transpose_cvt(const float* __restrict__ srcP,
                                                     const float* __restrict__ srcQ,
                                                     int twoSrc, int Rr, int Cc,
                                                     u16* __restrict__ dst) {
  int m = blockIdx.z;
  const float* src = twoSrc ? (((m & 1) ? srcQ : srcP) + (size_t)(m >> 1) * Rr * Cc)
                            : (srcP + (size_t)m * Rr * Cc);
  u16* d = dst + (size_t)m * Rr * Cc;
  __shared__ u16 t[32][34];
  int c0 = blockIdx.x * 32, r0 = blockIdx.y * 32;
  int tx = threadIdx.x, ty = threadIdx.y;   // 32 x 8
#pragma unroll
  for (int i = 0; i < 4; i++)
    t[ty + i * 8][tx] = f2b(src[(size_t)(r0 + ty + i * 8) * Cc + c0 + tx]);
  __syncthreads();
#pragma unroll
  for (int i = 0; i < 4; i++)
    d[(size_t)(c0 + ty + i * 8) * Rr + r0 + tx] = t[tx][ty + i * 8];
}

// ---------------- grouped GEMM: C[M,N] = A[M,K] * W^T (W stored [N][K] bf16) ----------------
__global__ __launch_bounds__(256)
void gemm_grouped(const u16* __restrict__ A, int lda,
                  const u16* __restrict__ W, int wShift, int K, int N,
                  const float* __restrict__ biasP, const float* __restrict__ biasQ,
                  int branchBias, int doGelu,
                  u16* __restrict__ outB, float* __restrict__ outF,
                  int doScatter, int ldo,
                  const int* __restrict__ gstart, const int* __restrict__ tileOff,
                  const int* __restrict__ perm) {
  __shared__ u16 As[TM * LDT];
  __shared__ u16 Bs[TN * LDT];

  int bidM = blockIdx.x;
  int tot = tileOff[16];
  if (bidM >= tot) return;
  int g = 0;
  while (g < 15 && bidM >= tileOff[g + 1]) g++;
  int rowStart = gstart[g] + (bidM - tileOff[g]) * TM;
  int rowEnd = gstart[g + 1];

  const u16* Wg = W + (size_t)(g >> wShift) * N * K;
  int e = g >> 1;
  const float* bias = ((branchBias && (g & 1)) ? biasQ : biasP) + (size_t)e * N;

  int tid = threadIdx.x;
  int lane = tid & 63;
  int wv = tid >> 6;
  int wm = (wv >> 1) * 64, wn = (wv & 1) * 64;
  int l15 = lane & 15, l4 = lane >> 4;
  int colBase = blockIdx.y * TN;

  f4 acc[4][4];
#pragma unroll
  for (int i = 0; i < 4; i++)
#pragma unroll
    for (int j = 0; j < 4; j++) acc[i][j] = (f4){0.f, 0.f, 0.f, 0.f};

  int sRow = tid >> 2;   // 0..63
  int sKq = tid & 3;     // 4 chunks of 8 bf16

  for (int k0 = 0; k0 < K; k0 += TK) {
    __syncthreads();
    // stage A tile [128][32] (row-clamped for partial tiles)
#pragma unroll
    for (int h = 0; h < 2; h++) {
      int r = sRow + h * 64;
      int gr = rowStart + r;
      int grc = gr < rowEnd ? gr : (rowEnd - 1);
      uint4 v = *reinterpret_cast<const uint4*>(A + (size_t)grc * lda + k0 + sKq * 8);
      *reinterpret_cast<uint4*>(&As[r * LDT + sKq * 8]) = v;
    }
    // stage B tile [128 n][32 k]  (W already [N][K])
#pragma unroll
    for (int h = 0; h < 2; h++) {
      int n = sRow + h * 64;
      uint4 v = *reinterpret_cast<const uint4*>(Wg + (size_t)(colBase + n) * K + k0 + sKq * 8);
      *reinterpret_cast<uint4*>(&Bs[n * LDT + sKq * 8]) = v;
    }
    __syncthreads();

    bh8 a[4], b[4];
#pragma unroll
    for (int i = 0; i < 4; i++)
      a[i] = *reinterpret_cast<const bh8*>(&As[(wm + i * 16 + l15) * LDT + l4 * 8]);
#pragma unroll
    for (int j = 0; j < 4; j++)
      b[j] = *reinterpret_cast<const bh8*>(&Bs[(wn + j * 16 + l15) * LDT + l4 * 8]);
#pragma unroll
    for (int i = 0; i < 4; i++)
#pragma unroll
      for (int j = 0; j < 4; j++)
        acc[i][j] = __builtin_amdgcn_mfma_f32_16x16x32_bf16(a[i], b[j], acc[i][j], 0, 0, 0);
  }

  // epilogue: C row = rowStart + wm + i*16 + l4*4 + r ; col = colBase + wn + j*16 + l15
#pragma unroll
  for (int i = 0; i < 4; i++) {
#pragma unroll
    for (int r = 0; r < 4; r++) {
      int row = rowStart + wm + i * 16 + l4 * 4 + r;
      if (row < rowEnd) {
        int orow = doScatter ? perm[row] : row;
#pragma unroll
        for (int j = 0; j < 4; j++) {
          int col = colBase + wn + j * 16 + l15;
          float v = acc[i][j][r] + bias[col];
          if (doGelu) v = gelu_f(v);
          if (outF) outF[(size_t)orow * ldo + col] = v;
          else      outB[(size_t)orow * ldo + col] = f2b(v);
        }
      }
    }
  }
}

// ---------------- LayerNorm over D=1024, grouped rows (fp32 in, bf16 out) ----------------
__global__ __launch_bounds__(256) void ln_kernel(const float* __restrict__ MIX,
                                                 u16* __restrict__ NRM,
                                                 const float* __restrict__ lng,
                                                 const float* __restrict__ lnb,
                                                 const int* __restrict__ gstart) {
  const int D = 1024;
  int pos = blockIdx.x;
  int g = 0;
  while (g < 15 && pos >= gstart[g + 1]) g++;
  int e = g >> 1;
  int tid = threadIdx.x;
  float x[4];
  float s = 0.f, s2 = 0.f;
#pragma unroll
  for (int i = 0; i < 4; i++) {
    float v = MIX[(size_t)pos * D + tid + i * 256];
    x[i] = v; s += v; s2 += v * v;
  }
#pragma unroll
  for (int off = 32; off >= 1; off >>= 1) {
    s += __shfl_down(s, off);
    s2 += __shfl_down(s2, off);
  }
  __shared__ float red[8];
  int wv = tid >> 6;
  if ((tid & 63) == 0) { red[wv] = s; red[4 + wv] = s2; }
  __syncthreads();
  if (tid == 0) {
    red[0] = red[0] + red[1] + red[2] + red[3];
    red[4] = red[4] + red[5] + red[6] + red[7];
  }
  __syncthreads();
  float mean = red[0] / D;
  float var = red[4] / D - mean * mean;
  float rstd = rsqrtf(var + 1e-5f);
#pragma unroll
  for (int i = 0; i < 4; i++) {
    int c = tid + i * 256;
    float v = (x[i] - mean) * rstd * lng[(size_t)e * D + c] + lnb[(size_t)e * D + c];
    NRM[(size_t)pos * D + c] = f2b(v);
  }
}

extern "C" void kernel_launch(void* const* d_in, const int* in_sizes, int n_in,
                              void* d_out, int out_size, void* d_ws, size_t ws_size,
                              hipStream_t stream) {
  const float* raw = (const float*)d_in[0];
  const int* hasp = (const int*)d_in[1];
  const int* eidx = (const int*)d_in[2];
  const float* pw1 = (const float*)d_in[3];  const float* pb1 = (const float*)d_in[4];
  const float* pw2 = (const float*)d_in[5];  const float* pb2 = (const float*)d_in[6];
  const float* qw1 = (const float*)d_in[7];  const float* qb1 = (const float*)d_in[8];
  const float* qw2 = (const float*)d_in[9];  const float* qb2 = (const float*)d_in[10];
  const float* lng = (const float*)d_in[11]; const float* lnb = (const float*)d_in[12];
  const float* tw1 = (const float*)d_in[13]; const float* tb1 = (const float*)d_in[14];
  const float* tw2 = (const float*)d_in[15]; const float* tb2 = (const float*)d_in[16];
  float* out = (float*)d_out;

  const int B = in_sizes[0] / 64;   // 8192
  const int S = 64, H = 2048, D = 1024, E = 8;

  char* ws = (char*)d_ws;
  size_t o = 0;
  int* R    = (int*)(ws + o); o += 1024;
  int* grp  = (int*)(ws + o); o += (size_t)B * 4;
  int* perm = (int*)(ws + o); o += (size_t)B * 4;
  u16* Xg   = (u16*)(ws + o); o += (size_t)B * S * 2;
  u16* Hbuf = (u16*)(ws + o); o += (size_t)B * H * 2;
  float* MIX = (float*)(ws + o); o += (size_t)B * D * 4;
  u16* NRM  = (u16*)(ws + o); o += (size_t)B * D * 2;
  u16* W1T  = (u16*)(ws + o); o += (size_t)2 * E * S * H * 2;
  u16* WB   = (u16*)(ws + o);                      // 64MB region, reused
  u16* T1T  = WB;
  u16* T2T  = WB + (size_t)E * D * H;

  int* gstart = R + 32;
  int* toff = R + 64;

  // routing
  init_routing<<<1, 128, 0, stream>>>(R);
  hist_kernel<<<B / 256, 256, 0, stream>>>(eidx, hasp, R, grp);
  scan_kernel<<<1, 64, 0, stream>>>(R);
  scatter_kernel<<<B / 256, 256, 0, stream>>>(grp, R, perm);
  gather_kernel<<<B / 4, 256, 0, stream>>>(raw, perm, Xg);

  dim3 tb(32, 8);
  // W1: [S=64][H=2048] x16 -> [H][S] bf16
  transpose_cvt<<<dim3(H / 32, S / 32, 16), tb, 0, stream>>>(pw1, qw1, 1, S, H, W1T);
  // W2: [H][D] x16 -> [D][H] bf16
  transpose_cvt<<<dim3(D / 32, H / 32, 16), tb, 0, stream>>>(pw2, qw2, 1, H, D, WB);

  const int maxT = B / TM + 16;
  // stage1: [B,64] x [64,2048] -> gelu -> Hbuf (bf16)
  gemm_grouped<<<dim3(maxT, H / TN), 256, 0, stream>>>(
      Xg, S, W1T, 0, S, H, pb1, qb1, 1, 1, Hbuf, nullptr, 0, H, gstart, toff, perm);
  // stage2: [B,2048] x [2048,1024] -> MIX (fp32)
  gemm_grouped<<<dim3(maxT, D / TN), 256, 0, stream>>>(
      Hbuf, H, WB, 0, H, D, pb2, qb2, 1, 0, nullptr, MIX, 0, D, gstart, toff, perm);
  // LayerNorm
  ln_kernel<<<B, 256, 0, stream>>>(MIX, NRM, lng, lnb, gstart);
  // T1: [D][H] x8 -> [H][D] ; T2: [H][D] x8 -> [D][H]  (overwrites WB, stage2 done)
  transpose_cvt<<<dim3(H / 32, D / 32, 8), tb, 0, stream>>>(tw1, nullptr, 0, D, H, T1T);
  transpose_cvt<<<dim3(D / 32, H / 32, 8), tb, 0, stream>>>(tw2, nullptr, 0, H, D, T2T);
  // stage3: [B,1024] x [1024,2048] -> gelu -> Hbuf (bf16)
  gemm_grouped<<<dim3(maxT, H / TN), 256, 0, stream>>>(
      NRM, D, T1T, 1, D, H, tb1, nullptr, 0, 1, Hbuf, nullptr, 0, H, gstart, toff, perm);
  // stage4: [B,2048] x [2048,1024] -> scatter fp32 to out
  gemm_grouped<<<dim3(maxT, D / TN), 256, 0, stream>>>(
      Hbuf, H, T2T, 1, H, D, tb2, nullptr, 0, 0, nullptr, out, 1, D, gstart, toff, perm);
}

// Round 3
// 652.985 us; speedup vs baseline: 1.0323x; 1.0323x over previous
//
#include <hip/hip_runtime.h>
#include <math.h>

typedef unsigned short u16;
typedef unsigned int   u32;
typedef __attribute__((ext_vector_type(8))) short bh8;   // 8 bf16 (4 VGPR)
typedef __attribute__((ext_vector_type(4))) float f4;    // 4 fp32 acc

#define TM 128
#define TN 128
#define TK 32   // LDS k-stride = 32 bf16 = 64 B, UNPADDED (global_load_lds requirement)

__device__ __forceinline__ u16 f2b(float f) {
  u32 u = __builtin_bit_cast(u32, f);
  u += 0x7fffu + ((u >> 16) & 1u);   // round-to-nearest-even
  return (u16)(u >> 16);
}
__device__ __forceinline__ float gelu_f(float x) {
  return 0.5f * x * (1.0f + erff(x * 0.70710678118654752f));
}

// async global -> LDS, 16 B per lane; lds base must be wave-uniform
__device__ __forceinline__ void gl2lds16(const u16* g, u16* l) {
  __builtin_amdgcn_global_load_lds(
      (const __attribute__((address_space(1))) u32*)g,
      (__attribute__((address_space(3))) u32*)l, 16, 0, 0);
}

// ---------------- routing ----------------
__global__ __launch_bounds__(128) void init_routing(int* __restrict__ R) {
  R[threadIdx.x] = 0;
}

__global__ __launch_bounds__(256) void hist_kernel(const int* __restrict__ eidx,
                                                   const int* __restrict__ hasp,
                                                   int* __restrict__ R,
                                                   int* __restrict__ grp) {
  int t = blockIdx.x * 256 + threadIdx.x;
  int g = eidx[t] * 2 + (hasp[t] != 0 ? 1 : 0);
  grp[t] = g;
  atomicAdd(&R[g], 1);
}

__global__ __launch_bounds__(64) void scan_kernel(int* __restrict__ R) {
  if (threadIdx.x == 0) {
    int* cnt = R; int* cur = R + 16; int* gs = R + 32; int* to = R + 64;
    gs[0] = 0; to[0] = 0;
    for (int g = 0; g < 16; g++) {
      gs[g + 1] = gs[g] + cnt[g];
      cur[g] = gs[g];
      to[g + 1] = to[g] + (cnt[g] + TM - 1) / TM;
    }
  }
}

__global__ __launch_bounds__(256) void scatter_kernel(const int* __restrict__ grp,
                                                      int* __restrict__ R,
                                                      int* __restrict__ perm) {
  int t = blockIdx.x * 256 + threadIdx.x;
  int g = grp[t];
  int pos = atomicAdd(&R[16 + g], 1);
  perm[pos] = t;
}

// gather raw_state (fp32) into grouped order, convert to bf16
__global__ __launch_bounds__(256) void gather_kernel(const float* __restrict__ raw,
                                                     const int* __restrict__ perm,
                                                     u16* __restrict__ Xg) {
  int t = blockIdx.x * 256 + threadIdx.x;
  int pos = t >> 6, ln = t & 63;
  int orig = perm[pos];
  Xg[(size_t)pos * 64 + ln] = f2b(raw[(size_t)orig * 64 + ln]);
}

// ------- weight transpose+convert: src fp32 [R][C] -> dst bf16 [C][R], 64x64 tiles -------
__global__ __launch_bounds__(256) void transpose_cvt(const float* __restrict__ srcP,
                                                     const float* __restrict__ srcQ,
                                                     int twoSrc, int Rr, int Cc,
                                                     u16* __restrict__ dst) {
  int m = blockIdx.z;
  const float* src = twoSrc ? (((m & 1) ? srcQ : srcP) + (size_t)(m >> 1) * Rr * Cc)
                            : (srcP + (size_t)m * Rr * Cc);
  u16* d = dst + (size_t)m * Rr * Cc;
  __shared__ u16 t[64][66];   // stride 66 u16 = 33 dword -> 2-way bank alias (free)
  int c0 = blockIdx.x * 64, r0 = blockIdx.y * 64;
  int tx = threadIdx.x, ty = threadIdx.y;   // 64 x 4
#pragma unroll
  for (int i = 0; i < 16; i++) {
    int r = ty + i * 4;
    t[tx][r] = f2b(src[(size_t)(r0 + r) * Cc + c0 + tx]);   // 256B coalesced read / wave
  }
  __syncthreads();
#pragma unroll
  for (int i = 0; i < 16; i++) {
    int c = ty + i * 4;
    d[(size_t)(c0 + c) * Rr + r0 + tx] = t[c][tx];          // 128B coalesced write / wave
  }
}

// ---------------- grouped GEMM: C[M,N] = A[M,K] * W^T (W stored [N][K] bf16) ----------------
__global__ __launch_bounds__(256)
void gemm_grouped(const u16* __restrict__ A, int lda,
                  const u16* __restrict__ W, int wShift, int K, int N,
                  const float* __restrict__ biasP, const float* __restrict__ biasQ,
                  int branchBias, int doGelu,
                  u16* __restrict__ outB, float* __restrict__ outF,
                  int doScatter, int ldo,
                  const int* __restrict__ gstart, const int* __restrict__ tileOff,
                  const int* __restrict__ perm) {
  __shared__ __align__(16) u16 As[TM * TK];
  __shared__ __align__(16) u16 Bs[TN * TK];

  int bidM = blockIdx.x;
  int tot = tileOff[16];
  if (bidM >= tot) return;
  int g = 0;
  while (g < 15 && bidM >= tileOff[g + 1]) g++;
  int rowStart = gstart[g] + (bidM - tileOff[g]) * TM;
  int rowEnd = gstart[g + 1];

  const u16* Wg = W + (size_t)(g >> wShift) * N * K;
  int e = g >> 1;
  const float* bias = ((branchBias && (g & 1)) ? biasQ : biasP) + (size_t)e * N;

  int tid = threadIdx.x;
  int lane = tid & 63;
  int wv = tid >> 6;
  int wm = (wv >> 1) * 64, wn = (wv & 1) * 64;
  int l15 = lane & 15, l4 = lane >> 4;
  int colBase = blockIdx.y * TN;

  // staging geometry: chunk c covers LDS rows c*16..c*16+15 (1024 B); this wave
  // owns chunks c0 = wv*2 and c0+1.  lane covers row c*16 + lane/4, kq = lane&3.
  int cA = wv * 2;
  int rA0 = cA * 16 + (lane >> 2);
  int rA1 = rA0 + 16;
  int kq8 = (lane & 3) * 8;
  int grA0 = rowStart + rA0; grA0 = grA0 < rowEnd ? grA0 : (rowEnd - 1);
  int grA1 = rowStart + rA1; grA1 = grA1 < rowEnd ? grA1 : (rowEnd - 1);
  const u16* aSrc0 = A + (size_t)grA0 * lda + kq8;
  const u16* aSrc1 = A + (size_t)grA1 * lda + kq8;
  const u16* bSrc0 = Wg + (size_t)(colBase + rA0) * K + kq8;
  const u16* bSrc1 = Wg + (size_t)(colBase + rA1) * K + kq8;
  u16* aDst0 = &As[cA * 512];
  u16* aDst1 = &As[cA * 512 + 512];
  u16* bDst0 = &Bs[cA * 512];
  u16* bDst1 = &Bs[cA * 512 + 512];

  f4 acc[4][4];
#pragma unroll
  for (int i = 0; i < 4; i++)
#pragma unroll
    for (int j = 0; j < 4; j++) acc[i][j] = (f4){0.f, 0.f, 0.f, 0.f};

  for (int k0 = 0; k0 < K; k0 += TK) {
    __syncthreads();   // previous iter's ds_reads done before overwrite
    gl2lds16(aSrc0 + k0, aDst0);
    gl2lds16(aSrc1 + k0, aDst1);
    gl2lds16(bSrc0 + k0, bDst0);
    gl2lds16(bSrc1 + k0, bDst1);
    __syncthreads();   // drains vmcnt(0): DMA complete + barrier

    bh8 a[4], b[4];
#pragma unroll
    for (int i = 0; i < 4; i++)
      a[i] = *reinterpret_cast<const bh8*>(&As[(wm + i * 16 + l15) * TK + l4 * 8]);
#pragma unroll
    for (int j = 0; j < 4; j++)
      b[j] = *reinterpret_cast<const bh8*>(&Bs[(wn + j * 16 + l15) * TK + l4 * 8]);
#pragma unroll
    for (int i = 0; i < 4; i++)
#pragma unroll
      for (int j = 0; j < 4; j++)
        acc[i][j] = __builtin_amdgcn_mfma_f32_16x16x32_bf16(a[i], b[j], acc[i][j], 0, 0, 0);
  }

  // epilogue: C row = rowStart + wm + i*16 + l4*4 + r ; col = colBase + wn + j*16 + l15
#pragma unroll
  for (int i = 0; i < 4; i++) {
#pragma unroll
    for (int r = 0; r < 4; r++) {
      int row = rowStart + wm + i * 16 + l4 * 4 + r;
      if (row < rowEnd) {
        int orow = doScatter ? perm[row] : row;
#pragma unroll
        for (int j = 0; j < 4; j++) {
          int col = colBase + wn + j * 16 + l15;
          float v = acc[i][j][r] + bias[col];
          if (doGelu) v = gelu_f(v);
          if (outF) outF[(size_t)orow * ldo + col] = v;
          else      outB[(size_t)orow * ldo + col] = f2b(v);
        }
      }
    }
  }
}

// ---------------- LayerNorm over D=1024, grouped rows (fp32 in, bf16 out) ----------------
__global__ __launch_bounds__(256) void ln_kernel(const float* __restrict__ MIX,
                                                 u16* __restrict__ NRM,
                                                 const float* __restrict__ lng,
                                                 const float* __restrict__ lnb,
                                                 const int* __restrict__ gstart) {
  const int D = 1024;
  int pos = blockIdx.x;
  int g = 0;
  while (g < 15 && pos >= gstart[g + 1]) g++;
  int e = g >> 1;
  int tid = threadIdx.x;
  float x[4];
  float s = 0.f, s2 = 0.f;
#pragma unroll
  for (int i = 0; i < 4; i++) {
    float v = MIX[(size_t)pos * D + tid + i * 256];
    x[i] = v; s += v; s2 += v * v;
  }
#pragma unroll
  for (int off = 32; off >= 1; off >>= 1) {
    s += __shfl_down(s, off);
    s2 += __shfl_down(s2, off);
  }
  __shared__ float red[8];
  int wv = tid >> 6;
  if ((tid & 63) == 0) { red[wv] = s; red[4 + wv] = s2; }
  __syncthreads();
  if (tid == 0) {
    red[0] = red[0] + red[1] + red[2] + red[3];
    red[4] = red[4] + red[5] + red[6] + red[7];
  }
  __syncthreads();
  float mean = red[0] / D;
  float var = red[4] / D - mean * mean;
  float rstd = rsqrtf(var + 1e-5f);
#pragma unroll
  for (int i = 0; i < 4; i++) {
    int c = tid + i * 256;
    float v = (x[i] - mean) * rstd * lng[(size_t)e * D + c] + lnb[(size_t)e * D + c];
    NRM[(size_t)pos * D + c] = f2b(v);
  }
}

extern "C" void kernel_launch(void* const* d_in, const int* in_sizes, int n_in,
                              void* d_out, int out_size, void* d_ws, size_t ws_size,
                              hipStream_t stream) {
  const float* raw = (const float*)d_in[0];
  const int* hasp = (const int*)d_in[1];
  const int* eidx = (const int*)d_in[2];
  const float* pw1 = (const float*)d_in[3];  const float* pb1 = (const float*)d_in[4];
  const float* pw2 = (const float*)d_in[5];  const float* pb2 = (const float*)d_in[6];
  const float* qw1 = (const float*)d_in[7];  const float* qb1 = (const float*)d_in[8];
  const float* qw2 = (const float*)d_in[9];  const float* qb2 = (const float*)d_in[10];
  const float* lng = (const float*)d_in[11]; const float* lnb = (const float*)d_in[12];
  const float* tw1 = (const float*)d_in[13]; const float* tb1 = (const float*)d_in[14];
  const float* tw2 = (const float*)d_in[15]; const float* tb2 = (const float*)d_in[16];
  float* out = (float*)d_out;

  const int B = in_sizes[0] / 64;   // 8192
  const int S = 64, H = 2048, D = 1024, E = 8;

  char* ws = (char*)d_ws;
  size_t o = 0;
  int* R    = (int*)(ws + o); o += 1024;
  int* grp  = (int*)(ws + o); o += (size_t)B * 4;
  int* perm = (int*)(ws + o); o += (size_t)B * 4;
  u16* Xg   = (u16*)(ws + o); o += (size_t)B * S * 2;
  u16* Hbuf = (u16*)(ws + o); o += (size_t)B * H * 2;
  float* MIX = (float*)(ws + o); o += (size_t)B * D * 4;
  u16* NRM  = (u16*)(ws + o); o += (size_t)B * D * 2;
  u16* W1T  = (u16*)(ws + o); o += (size_t)2 * E * S * H * 2;
  u16* WB   = (u16*)(ws + o);                      // 64MB region, reused
  u16* T1T  = WB;
  u16* T2T  = WB + (size_t)E * D * H;

  int* gstart = R + 32;
  int* toff = R + 64;

  // routing
  init_routing<<<1, 128, 0, stream>>>(R);
  hist_kernel<<<B / 256, 256, 0, stream>>>(eidx, hasp, R, grp);
  scan_kernel<<<1, 64, 0, stream>>>(R);
  scatter_kernel<<<B / 256, 256, 0, stream>>>(grp, R, perm);
  gather_kernel<<<B / 4, 256, 0, stream>>>(raw, perm, Xg);

  dim3 tb(64, 4);
  // W1: [S=64][H=2048] x16 -> [H][S] bf16
  transpose_cvt<<<dim3(H / 64, S / 64, 16), tb, 0, stream>>>(pw1, qw1, 1, S, H, W1T);
  // W2: [H][D] x16 -> [D][H] bf16
  transpose_cvt<<<dim3(D / 64, H / 64, 16), tb, 0, stream>>>(pw2, qw2, 1, H, D, WB);

  const int maxT = B / TM + 16;
  // stage1: [B,64] x [64,2048] -> gelu -> Hbuf (bf16)
  gemm_grouped<<<dim3(maxT, H / TN), 256, 0, stream>>>(
      Xg, S, W1T, 0, S, H, pb1, qb1, 1, 1, Hbuf, nullptr, 0, H, gstart, toff, perm);
  // stage2: [B,2048] x [2048,1024] -> MIX (fp32)
  gemm_grouped<<<dim3(maxT, D / TN), 256, 0, stream>>>(
      Hbuf, H, WB, 0, H, D, pb2, qb2, 1, 0, nullptr, MIX, 0, D, gstart, toff, perm);
  // LayerNorm
  ln_kernel<<<B, 256, 0, stream>>>(MIX, NRM, lng, lnb, gstart);
  // T1: [D][H] x8 -> [H][D] ; T2: [H][D] x8 -> [D][H]  (overwrites WB, stage2 done)
  transpose_cvt<<<dim3(H / 64, D / 64, 8), tb, 0, stream>>>(tw1, nullptr, 0, D, H, T1T);
  transpose_cvt<<<dim3(D / 64, H / 64, 8), tb, 0, stream>>>(tw2, nullptr, 0, H, D, T2T);
  // stage3: [B,1024] x [1024,2048] -> gelu -> Hbuf (bf16)
  gemm_grouped<<<dim3(maxT, H / TN), 256, 0, stream>>>(
      NRM, D, T1T, 1, D, H, tb1, nullptr, 0, 1, Hbuf, nullptr, 0, H, gstart, toff, perm);
  // stage4: [B,2048] x [2048,1024] -> scatter fp32 to out
  gemm_grouped<<<dim3(maxT, D / TN), 256, 0, stream>>>(
      Hbuf, H, T2T, 1, H, D, tb2, nullptr, 0, 0, nullptr, out, 1, D, gstart, toff, perm);
}